// Round 16
// baseline (167.961 us; speedup 1.0000x reference)
//
#include <hip/hip_runtime.h>
#include <math.h>

#define N_TOK 2048
#define DM    1024
#define HD    2048
#define NE    8
#define RMAX  5120                /* 4096 + 8*128 pad */
#define TMAX  40                  /* max 128-row tiles */
#define KSPL  2                   /* ffn2 K-split */

#define GATE_BLKS 512             /* N_TOK/4 */
#define XCVT_BLKS 1024            /* N_TOK*DM/(256*8) */
#define PREP_BLKS (GATE_BLKS + XCVT_BLKS)

typedef short short8 __attribute__((ext_vector_type(8)));
typedef unsigned short u16x8 __attribute__((ext_vector_type(8)));
typedef float f32x4  __attribute__((ext_vector_type(4)));

__device__ inline unsigned short f2b(float f) {   // fp32 -> bf16 RNE
  unsigned int u = __float_as_uint(f);
  return (unsigned short)((u + 0x7FFFu + ((u >> 16) & 1u)) >> 16);
}
__device__ inline float b2f(unsigned short s) {
  return __uint_as_float(((unsigned int)s) << 16);
}
__device__ inline void gload_lds16(const void* g, void* l) {
  __builtin_amdgcn_global_load_lds(
      (const __attribute__((address_space(1))) unsigned int*)g,
      (__attribute__((address_space(3))) unsigned int*)l, 16, 0, 0);
}

// ---------------------------------------------------------------- prep
// gate (512 blocks) + x-convert (1024 blocks). No weight conversion.
__global__ __launch_bounds__(256) void prep_kernel(
    const float* __restrict__ inp, const float* __restrict__ Wg,
    const float* __restrict__ bg,
    int* __restrict__ top_idx, float* __restrict__ gate_w,
    unsigned short* __restrict__ Xb) {
  int bid = blockIdx.x;
  if (bid < GATE_BLKS) {
    int wave = threadIdx.x >> 6;
    int lane = threadIdx.x & 63;
    int n = bid * 4 + wave;
    float acc[NE];
#pragma unroll
    for (int e = 0; e < NE; ++e) acc[e] = 0.f;
    const float4* wg4 = reinterpret_cast<const float4*>(Wg);
#pragma unroll
    for (int i = 0; i < DM / 64; ++i) {
      int d = i * 64 + lane;
      float x = inp[n * DM + d];
      float4 w0 = wg4[d * 2 + 0];
      float4 w1 = wg4[d * 2 + 1];
      acc[0] += x * w0.x; acc[1] += x * w0.y; acc[2] += x * w0.z; acc[3] += x * w0.w;
      acc[4] += x * w1.x; acc[5] += x * w1.y; acc[6] += x * w1.z; acc[7] += x * w1.w;
    }
#pragma unroll
    for (int off = 32; off > 0; off >>= 1) {
#pragma unroll
      for (int e = 0; e < NE; ++e) acc[e] += __shfl_xor(acc[e], off);
    }
    if (lane == 0) {
      float v0 = -1e30f, v1 = -1e30f; int i0 = -1, i1 = -1;
#pragma unroll
      for (int e = 0; e < NE; ++e) {
        float v = acc[e] + bg[e];
        if (v > v0)      { v1 = v0; i1 = i0; v0 = v; i0 = e; }
        else if (v > v1) { v1 = v;  i1 = e; }
      }
      float e1 = expf(v1 - v0);
      float s  = 1.f + e1;
      top_idx[n * 2]     = i0;
      top_idx[n * 2 + 1] = i1;
      gate_w[n * 2]      = 1.f / s;
      gate_w[n * 2 + 1]  = e1 / s;
    }
  } else {
    int i = ((bid - GATE_BLKS) * 256 + threadIdx.x) * 8;
    float4 a = *(const float4*)(inp + i);
    float4 b = *(const float4*)(inp + i + 4);
    ushort4 pa, pb;
    pa.x = f2b(a.x); pa.y = f2b(a.y); pa.z = f2b(a.z); pa.w = f2b(a.w);
    pb.x = f2b(b.x); pb.y = f2b(b.y); pb.z = f2b(b.z); pb.w = f2b(b.w);
    *(ushort4*)(Xb + i)     = pa;
    *(ushort4*)(Xb + i + 4) = pb;
  }
}

// ---------------------------------------------------------------- group
__global__ __launch_bounds__(1024) void group_kernel(
    const int* __restrict__ top_idx,
    int* __restrict__ token_of, int* __restrict__ inv_g,
    int* __restrict__ tile_expert, int* __restrict__ tile_row0,
    int* __restrict__ n_tiles) {
  __shared__ int s_wtot[16];
  int tid = threadIdx.x, lane = tid & 63, wid = tid >> 6;
  int base = 0, tiles = 0;
  for (int e = 0; e < NE; ++e) {
    int cnt = 0;
#pragma unroll
    for (int c0 = 0; c0 < N_TOK; c0 += 1024) {
      int n = c0 + tid;
      int t0 = top_idx[n * 2], t1 = top_idx[n * 2 + 1];
      bool f = (t0 == e) || (t1 == e);
      int k = (t0 == e) ? 0 : 1;
      unsigned long long m = __ballot(f);
      int lp = __popcll(m & ((1ull << lane) - 1ull));
      if (lane == 0) s_wtot[wid] = __popcll(m);
      __syncthreads();
      int wbase = 0, tot = 0;
#pragma unroll
      for (int w = 0; w < 16; ++w) {
        int c = s_wtot[w];
        if (w < wid) wbase += c;
        tot += c;
      }
      if (f) {
        int pos = base + cnt + wbase + lp;
        token_of[pos] = n;
        inv_g[n * 2 + k] = pos;
      }
      cnt += tot;
      __syncthreads();
    }
    int padded = (cnt + 127) & ~127;
    for (int i = cnt + tid; i < padded; i += 1024) token_of[base + i] = -1;
    if (tid == 0) {
      for (int t = 0; t < padded / 128; ++t) {
        tile_expert[tiles + t] = e;
        tile_row0[tiles + t]   = base + t * 128;
      }
    }
    tiles += padded / 128;
    base  += padded;
    __syncthreads();
  }
  if (tid == 0) n_tiles[0] = tiles;
}

// ---------------------------------------------------------------- ffn1
// 128x64 tile, BK=32, XCD swizzle (4 units/XCD). 3-buffer LDS, ONE raw
// barrier per phase, counted vmcnt(10) (never 0 until last phase).
// A: bf16 gload_lds slot-swizzled; B: fp32 W1 -> regs -> bf16 -> ds_write.
__global__ __launch_bounds__(256, 4) void ffn1_mfma(
    const unsigned short* __restrict__ Xb,
    const float* __restrict__ W1,
    const float* __restrict__ b1,
    const unsigned short* __restrict__ Xzero,
    const int* __restrict__ token_of, const int* __restrict__ tile_expert,
    const int* __restrict__ tile_row0, const int* __restrict__ n_tiles,
    unsigned short* __restrict__ Hbuf) {
  int lin  = blockIdx.x;
  int xcd  = lin & 7, slot = lin >> 3;
  int unit = xcd * 4 + slot / TMAX;        // 0..31 col unit
  int t    = slot % TMAX;
  if (t >= n_tiles[0]) return;
  int e    = tile_expert[t];
  int row0 = tile_row0[t];
  int h0   = unit * 64;
  __shared__ __align__(16) unsigned short Asl[3][128][32];   // 24 KB
  __shared__ __align__(16) unsigned short Bsl[3][4][64][8];  // 12 KB
  int tid = threadIdx.x, lane = tid & 63;
  int wid = tid >> 6, wr = wid >> 1, wc = wid & 1;
  int l15 = lane & 15, l4 = lane >> 4;
  int sw  = (l15 >> 1) & 3;

  int ar[2], asg[2], tk[2];
#pragma unroll
  for (int q = 0; q < 2; ++q) {
    int idx = tid + q * 256;
    ar[q]  = idx >> 2;
    asg[q] = (idx & 3) ^ ((ar[q] >> 1) & 3);
    tk[q]  = token_of[row0 + ar[q]];
  }
  int bcol = tid & 63, bks = tid >> 6;
  const float* W1e = W1 + (size_t)e * DM * HD;

  f32x4 acc[4][2] = {};
  float bvA[8], bvB[8];

  auto issueB = [&](int tt, float* bv) {   // 8 fp32 loads -> regs
    const float* p = W1e + (size_t)(tt * 32 + bks * 8) * HD + h0 + bcol;
#pragma unroll
    for (int i = 0; i < 8; ++i) bv[i] = p[(size_t)i * HD];
  };
  auto packwrite = [&](const float* bv, int buf) {
    u16x8 o;
#pragma unroll
    for (int i = 0; i < 8; ++i) o[i] = f2b(bv[i]);
    *(u16x8*)&Bsl[buf][bks][bcol][0] = o;
  };
  auto issueA = [&](int tt, int buf) {     // 2 gload_lds
#pragma unroll
    for (int q = 0; q < 2; ++q) {
      int idx = tid + q * 256;
      const unsigned short* ga = (tk[q] < 0)
          ? Xzero
          : Xb + (size_t)tk[q] * DM + tt * 32 + asg[q] * 8;
      gload_lds16(ga, (char*)&Asl[buf][0][0] + (size_t)idx * 16);
    }
  };
  auto compute = [&](int buf) {
    short8 a[4], b[2];
#pragma unroll
    for (int m = 0; m < 4; ++m) {
      int R = wr * 64 + m * 16 + l15;
      a[m] = *(const short8*)((const char*)&Asl[buf][0][0] + R * 64 + ((l4 ^ sw) << 4));
    }
#pragma unroll
    for (int n = 0; n < 2; ++n)
      b[n] = *(const short8*)&Bsl[buf][l4][wc * 32 + n * 16 + l15][0];
#pragma unroll
    for (int m = 0; m < 4; ++m)
#pragma unroll
      for (int n = 0; n < 2; ++n)
        acc[m][n] = __builtin_amdgcn_mfma_f32_16x16x32_bf16(a[m], b[n], acc[m][n], 0, 0, 0);
  };

  // prologue: two phases in flight
  issueB(0, bvA); issueA(0, 0);
  issueB(1, bvB); issueA(1, 1);
  int buf = 0;
  for (int kt = 0; kt < 32; ++kt) {
    packwrite((kt & 1) ? bvB : bvA, buf);  // compiler: counted vmcnt for bv
    if (kt < 31) asm volatile("s_waitcnt vmcnt(10)" ::: "memory");
    else         asm volatile("s_waitcnt vmcnt(0)"  ::: "memory");
    asm volatile("s_waitcnt lgkmcnt(0)" ::: "memory");
    __builtin_amdgcn_s_barrier();
    __builtin_amdgcn_sched_barrier(0);
    compute(buf);
    if (kt + 2 < 32) {
      int nb = buf + 2; if (nb >= 3) nb -= 3;
      issueB(kt + 2, (kt & 1) ? bvB : bvA);
      issueA(kt + 2, nb);
    }
    if (++buf == 3) buf = 0;
  }

  float bias[2];
#pragma unroll
  for (int n = 0; n < 2; ++n) bias[n] = b1[e * HD + h0 + wc * 32 + n * 16 + l15];
#pragma unroll
  for (int m = 0; m < 4; ++m) {
#pragma unroll
    for (int n = 0; n < 2; ++n) {
      int col = h0 + wc * 32 + n * 16 + l15;
#pragma unroll
      for (int j = 0; j < 4; ++j) {
        int row = row0 + wr * 64 + m * 16 + l4 * 4 + j;
        float x = acc[m][n][j] + bias[n];
        float g = 0.5f * x * (1.f + tanhf(0.7978845608f * (x + 0.044715f * x * x * x)));
        Hbuf[(size_t)row * HD + col] = f2b(g);
      }
    }
  }
}

// ---------------------------------------------------------------- ffn2
// Same pipeline; K-split x2 over 32 units = (16 d-cols x 2 ks); fp32
// partials to Ypart; bias added by ks==0 only.
__global__ __launch_bounds__(256, 4) void ffn2_mfma(
    const unsigned short* __restrict__ Hbuf,
    const float* __restrict__ W2,
    const float* __restrict__ b2,
    const int* __restrict__ tile_expert, const int* __restrict__ tile_row0,
    const int* __restrict__ n_tiles,
    float* __restrict__ Ypart) {
  int lin  = blockIdx.x;
  int xcd  = lin & 7, slot = lin >> 3;
  int unit = xcd * 4 + slot / TMAX;        // 0..31
  int t    = slot % TMAX;
  if (t >= n_tiles[0]) return;
  int e    = tile_expert[t];
  int row0 = tile_row0[t];
  int d0   = (unit >> 1) * 64;
  int ks   = unit & 1;
  int kbase = ks * (HD / KSPL);            // 0 or 1024
  __shared__ __align__(16) unsigned short Asl[3][128][32];
  __shared__ __align__(16) unsigned short Bsl[3][4][64][8];
  int tid = threadIdx.x, lane = tid & 63;
  int wid = tid >> 6, wr = wid >> 1, wc = wid & 1;
  int l15 = lane & 15, l4 = lane >> 4;
  int sw  = (l15 >> 1) & 3;

  int ar[2], asg[2];
#pragma unroll
  for (int q = 0; q < 2; ++q) {
    int idx = tid + q * 256;
    ar[q]  = idx >> 2;
    asg[q] = (idx & 3) ^ ((ar[q] >> 1) & 3);
  }
  int bcol = tid & 63, bks = tid >> 6;
  const float* W2e = W2 + (size_t)e * HD * DM + (size_t)kbase * DM;

  f32x4 acc[4][2] = {};
  float bvA[8], bvB[8];

  auto issueB = [&](int tt, float* bv) {
    const float* p = W2e + (size_t)(tt * 32 + bks * 8) * DM + d0 + bcol;
#pragma unroll
    for (int i = 0; i < 8; ++i) bv[i] = p[(size_t)i * DM];
  };
  auto packwrite = [&](const float* bv, int buf) {
    u16x8 o;
#pragma unroll
    for (int i = 0; i < 8; ++i) o[i] = f2b(bv[i]);
    *(u16x8*)&Bsl[buf][bks][bcol][0] = o;
  };
  auto issueA = [&](int tt, int buf) {
#pragma unroll
    for (int q = 0; q < 2; ++q) {
      int idx = tid + q * 256;
      const unsigned short* ga =
          Hbuf + (size_t)(row0 + ar[q]) * HD + kbase + tt * 32 + asg[q] * 8;
      gload_lds16(ga, (char*)&Asl[buf][0][0] + (size_t)idx * 16);
    }
  };
  auto compute = [&](int buf) {
    short8 a[4], b[2];
#pragma unroll
    for (int m = 0; m < 4; ++m) {
      int R = wr * 64 + m * 16 + l15;
      a[m] = *(const short8*)((const char*)&Asl[buf][0][0] + R * 64 + ((l4 ^ sw) << 4));
    }
#pragma unroll
    for (int n = 0; n < 2; ++n)
      b[n] = *(const short8*)&Bsl[buf][l4][wc * 32 + n * 16 + l15][0];
#pragma unroll
    for (int m = 0; m < 4; ++m)
#pragma unroll
      for (int n = 0; n < 2; ++n)
        acc[m][n] = __builtin_amdgcn_mfma_f32_16x16x32_bf16(a[m], b[n], acc[m][n], 0, 0, 0);
  };

  const int NT = HD / KSPL / 32;           // 32
  issueB(0, bvA); issueA(0, 0);
  issueB(1, bvB); issueA(1, 1);
  int buf = 0;
  for (int kt = 0; kt < NT; ++kt) {
    packwrite((kt & 1) ? bvB : bvA, buf);
    if (kt < NT - 1) asm volatile("s_waitcnt vmcnt(10)" ::: "memory");
    else             asm volatile("s_waitcnt vmcnt(0)"  ::: "memory");
    asm volatile("s_waitcnt lgkmcnt(0)" ::: "memory");
    __builtin_amdgcn_s_barrier();
    __builtin_amdgcn_sched_barrier(0);
    compute(buf);
    if (kt + 2 < NT) {
      int nb = buf + 2; if (nb >= 3) nb -= 3;
      issueB(kt + 2, (kt & 1) ? bvB : bvA);
      issueA(kt + 2, nb);
    }
    if (++buf == 3) buf = 0;
  }

  float bias[2];
#pragma unroll
  for (int n = 0; n < 2; ++n)
    bias[n] = (ks == 0) ? b2[e * DM + d0 + wc * 32 + n * 16 + l15] : 0.f;
  float* Yp = Ypart + (size_t)ks * RMAX * DM;
#pragma unroll
  for (int m = 0; m < 4; ++m) {
#pragma unroll
    for (int n = 0; n < 2; ++n) {
      int col = d0 + wc * 32 + n * 16 + l15;
#pragma unroll
      for (int j = 0; j < 4; ++j) {
        int row = row0 + wr * 64 + m * 16 + l4 * 4 + j;
        Yp[(size_t)row * DM + col] = acc[m][n][j] + bias[n];
      }
    }
  }
}

// ---------------------------------------------------------------- combine
__global__ void combine_kernel(const float* __restrict__ Ypart,
                               const int* __restrict__ inv_g,
                               const float* __restrict__ gate_w,
                               float* __restrict__ out) {
  int n = blockIdx.x;
  int r0 = inv_g[n * 2], r1 = inv_g[n * 2 + 1];
  float g0 = gate_w[n * 2], g1 = gate_w[n * 2 + 1];
  int i = threadIdx.x;
  const float4* y00 = (const float4*)(Ypart + (size_t)r0 * DM);
  const float4* y01 = (const float4*)(Ypart + (size_t)(RMAX + r0) * DM);
  const float4* y10 = (const float4*)(Ypart + (size_t)r1 * DM);
  const float4* y11 = (const float4*)(Ypart + (size_t)(RMAX + r1) * DM);
  float4 a0 = y00[i], a1 = y01[i], b0 = y10[i], b1 = y11[i];
  float4 rv;
  rv.x = g0 * (a0.x + a1.x) + g1 * (b0.x + b1.x);
  rv.y = g0 * (a0.y + a1.y) + g1 * (b0.y + b1.y);
  rv.z = g0 * (a0.z + a1.z) + g1 * (b0.z + b1.z);
  rv.w = g0 * (a0.w + a1.w) + g1 * (b0.w + b1.w);
  *(float4*)(out + (size_t)n * DM + i * 4) = rv;
}

// ---------------------------------------------------------------- launch
extern "C" void kernel_launch(void* const* d_in, const int* in_sizes, int n_in,
                              void* d_out, int out_size, void* d_ws, size_t ws_size,
                              hipStream_t stream) {
  const float* inp = (const float*)d_in[0];
  const float* Wg  = (const float*)d_in[1];
  const float* bg  = (const float*)d_in[2];
  const float* W1  = (const float*)d_in[3];
  const float* b1  = (const float*)d_in[4];
  const float* W2  = (const float*)d_in[5];
  const float* b2  = (const float*)d_in[6];
  float* out = (float*)d_out;

  char* ws = (char*)d_ws;
  size_t off = 0;
  auto alloc = [&](size_t bytes) {
    size_t o = off;
    off = (off + bytes + 255) & ~(size_t)255;
    return o;
  };
  int*   top_idx     = (int*)  (ws + alloc(N_TOK * 2 * sizeof(int)));
  float* gate_w      = (float*)(ws + alloc(N_TOK * 2 * sizeof(float)));
  int*   token_of    = (int*)  (ws + alloc(RMAX * sizeof(int)));
  int*   inv_g       = (int*)  (ws + alloc(N_TOK * 2 * sizeof(int)));
  int*   tile_expert = (int*)  (ws + alloc(TMAX * sizeof(int)));
  int*   tile_row0   = (int*)  (ws + alloc(TMAX * sizeof(int)));
  int*   n_tiles     = (int*)  (ws + alloc(sizeof(int)));
  unsigned short* Xzero = (unsigned short*)(ws + alloc(DM * 2));
  unsigned short* Xb    = (unsigned short*)(ws + alloc((size_t)N_TOK * DM * 2));
  unsigned short* Hbuf  = (unsigned short*)(ws + alloc((size_t)RMAX * HD * 2));
  float*          Ypart = (float*)(ws + alloc((size_t)KSPL * RMAX * DM * 4));
  (void)ws_size;

  hipMemsetAsync(Xzero, 0, DM * 2, stream);
  prep_kernel<<<PREP_BLKS, 256, 0, stream>>>(inp, Wg, bg, top_idx, gate_w, Xb);
  group_kernel<<<1, 1024, 0, stream>>>(top_idx, token_of, inv_g,
                                       tile_expert, tile_row0, n_tiles);
  ffn1_mfma<<<8 * 4 * TMAX, 256, 0, stream>>>(
      Xb, W1, b1, Xzero, token_of, tile_expert, tile_row0, n_tiles, Hbuf);
  ffn2_mfma<<<8 * 4 * TMAX, 256, 0, stream>>>(
      Hbuf, W2, b2, tile_expert, tile_row0, n_tiles, Ypart);
  combine_kernel<<<N_TOK, 256, 0, stream>>>(Ypart, inv_g, gate_w, out);
}

// Round 17
// 151.574 us; speedup vs baseline: 1.1081x; 1.1081x over previous
//
#include <hip/hip_runtime.h>
#include <math.h>

#define N_TOK 2048
#define DM    1024
#define HD    2048
#define NE    8
#define RMAX  5120                /* 4096 + 8*128 pad */
#define TMAX  40                  /* max 128-row tiles */
#define KSPL  4                   /* ffn2 K-split */

#define GATE_BLKS 512             /* N_TOK/4 */
#define XCVT_BLKS 1024            /* N_TOK*DM/(256*8) */
#define PREP_BLKS (GATE_BLKS + XCVT_BLKS)

typedef short short8 __attribute__((ext_vector_type(8)));
typedef unsigned short u16x8 __attribute__((ext_vector_type(8)));
typedef float f32x4  __attribute__((ext_vector_type(4)));

__device__ inline unsigned short f2b(float f) {   // fp32 -> bf16 RNE
  unsigned int u = __float_as_uint(f);
  return (unsigned short)((u + 0x7FFFu + ((u >> 16) & 1u)) >> 16);
}
__device__ inline float b2f(unsigned short s) {
  return __uint_as_float(((unsigned int)s) << 16);
}
__device__ inline void gload_lds16(const void* g, void* l) {
  __builtin_amdgcn_global_load_lds(
      (const __attribute__((address_space(1))) unsigned int*)g,
      (__attribute__((address_space(3))) unsigned int*)l, 16, 0, 0);
}

// ---------------------------------------------------------------- prep
__global__ __launch_bounds__(256) void prep_kernel(
    const float* __restrict__ inp, const float* __restrict__ Wg,
    const float* __restrict__ bg,
    int* __restrict__ top_idx, float* __restrict__ gate_w,
    unsigned short* __restrict__ Xb) {
  int bid = blockIdx.x;
  if (bid < GATE_BLKS) {
    int wave = threadIdx.x >> 6;
    int lane = threadIdx.x & 63;
    int n = bid * 4 + wave;
    float acc[NE];
#pragma unroll
    for (int e = 0; e < NE; ++e) acc[e] = 0.f;
    const float4* wg4 = reinterpret_cast<const float4*>(Wg);
#pragma unroll
    for (int i = 0; i < DM / 64; ++i) {
      int d = i * 64 + lane;
      float x = inp[n * DM + d];
      float4 w0 = wg4[d * 2 + 0];
      float4 w1 = wg4[d * 2 + 1];
      acc[0] += x * w0.x; acc[1] += x * w0.y; acc[2] += x * w0.z; acc[3] += x * w0.w;
      acc[4] += x * w1.x; acc[5] += x * w1.y; acc[6] += x * w1.z; acc[7] += x * w1.w;
    }
#pragma unroll
    for (int off = 32; off > 0; off >>= 1) {
#pragma unroll
      for (int e = 0; e < NE; ++e) acc[e] += __shfl_xor(acc[e], off);
    }
    if (lane == 0) {
      float v0 = -1e30f, v1 = -1e30f; int i0 = -1, i1 = -1;
#pragma unroll
      for (int e = 0; e < NE; ++e) {
        float v = acc[e] + bg[e];
        if (v > v0)      { v1 = v0; i1 = i0; v0 = v; i0 = e; }
        else if (v > v1) { v1 = v;  i1 = e; }
      }
      float e1 = expf(v1 - v0);
      float s  = 1.f + e1;
      top_idx[n * 2]     = i0;
      top_idx[n * 2 + 1] = i1;
      gate_w[n * 2]      = 1.f / s;
      gate_w[n * 2 + 1]  = e1 / s;
    }
  } else {
    int i = ((bid - GATE_BLKS) * 256 + threadIdx.x) * 8;
    float4 a = *(const float4*)(inp + i);
    float4 b = *(const float4*)(inp + i + 4);
    ushort4 pa, pb;
    pa.x = f2b(a.x); pa.y = f2b(a.y); pa.z = f2b(a.z); pa.w = f2b(a.w);
    pb.x = f2b(b.x); pb.y = f2b(b.y); pb.z = f2b(b.z); pb.w = f2b(b.w);
    *(ushort4*)(Xb + i)     = pa;
    *(ushort4*)(Xb + i + 4) = pb;
  }
}

// ---------------------------------------------------------------- group
__global__ __launch_bounds__(1024) void group_kernel(
    const int* __restrict__ top_idx,
    int* __restrict__ token_of, int* __restrict__ inv_g,
    int* __restrict__ tile_expert, int* __restrict__ tile_row0,
    int* __restrict__ n_tiles) {
  __shared__ int s_wtot[16];
  int tid = threadIdx.x, lane = tid & 63, wid = tid >> 6;
  int base = 0, tiles = 0;
  for (int e = 0; e < NE; ++e) {
    int cnt = 0;
#pragma unroll
    for (int c0 = 0; c0 < N_TOK; c0 += 1024) {
      int n = c0 + tid;
      int t0 = top_idx[n * 2], t1 = top_idx[n * 2 + 1];
      bool f = (t0 == e) || (t1 == e);
      int k = (t0 == e) ? 0 : 1;
      unsigned long long m = __ballot(f);
      int lp = __popcll(m & ((1ull << lane) - 1ull));
      if (lane == 0) s_wtot[wid] = __popcll(m);
      __syncthreads();
      int wbase = 0, tot = 0;
#pragma unroll
      for (int w = 0; w < 16; ++w) {
        int c = s_wtot[w];
        if (w < wid) wbase += c;
        tot += c;
      }
      if (f) {
        int pos = base + cnt + wbase + lp;
        token_of[pos] = n;
        inv_g[n * 2 + k] = pos;
      }
      cnt += tot;
      __syncthreads();
    }
    int padded = (cnt + 127) & ~127;
    for (int i = cnt + tid; i < padded; i += 1024) token_of[base + i] = -1;
    if (tid == 0) {
      for (int t = 0; t < padded / 128; ++t) {
        tile_expert[tiles + t] = e;
        tile_row0[tiles + t]   = base + t * 128;
      }
    }
    tiles += padded / 128;
    base  += padded;
    __syncthreads();
  }
  if (tid == 0) n_tiles[0] = tiles;
}

// ---------------------------------------------------------------- ffn1
// R10 exact: 128x64 tile, BK=32, dbuf, XCD swizzle (4 units/XCD).
__global__ __launch_bounds__(256, 6) void ffn1_mfma(
    const unsigned short* __restrict__ Xb,
    const float* __restrict__ W1,
    const float* __restrict__ b1,
    const unsigned short* __restrict__ Xzero,
    const int* __restrict__ token_of, const int* __restrict__ tile_expert,
    const int* __restrict__ tile_row0, const int* __restrict__ n_tiles,
    unsigned short* __restrict__ Hbuf) {
  int lin  = blockIdx.x;
  int xcd  = lin & 7, slot = lin >> 3;
  int unit = xcd * 4 + slot / TMAX;        // 0..31 col unit
  int t    = slot % TMAX;
  if (t >= n_tiles[0]) return;
  int e    = tile_expert[t];
  int row0 = tile_row0[t];
  int h0   = unit * 64;
  __shared__ __align__(16) unsigned short Asl[2][128][32];
  __shared__ __align__(16) unsigned short Bsl[2][4][64][8];
  int tid = threadIdx.x, lane = tid & 63;
  int wid = tid >> 6, wr = wid >> 1, wc = wid & 1;
  int l15 = lane & 15, l4 = lane >> 4;
  int sw  = (l15 >> 1) & 3;

  int ar[2], asg[2], tk[2];
#pragma unroll
  for (int q = 0; q < 2; ++q) {
    int idx = tid + q * 256;
    ar[q]  = idx >> 2;
    asg[q] = (idx & 3) ^ ((ar[q] >> 1) & 3);
    tk[q]  = token_of[row0 + ar[q]];
  }
  int bcol = tid & 63, bks = tid >> 6;
  const float* W1e = W1 + (size_t)e * DM * HD;

  f32x4 acc[4][2] = {};
  float bvA[8], bvB[8];

  auto issueB = [&](int tt, float* bv) {
    const float* p = W1e + (size_t)(tt * 32 + bks * 8) * HD + h0 + bcol;
#pragma unroll
    for (int i = 0; i < 8; ++i) bv[i] = p[(size_t)i * HD];
  };
  auto packwrite = [&](const float* bv, int buf) {
    u16x8 o;
#pragma unroll
    for (int i = 0; i < 8; ++i) o[i] = f2b(bv[i]);
    *(u16x8*)&Bsl[buf][bks][bcol][0] = o;
  };
  auto issueA = [&](int tt, int buf) {
#pragma unroll
    for (int q = 0; q < 2; ++q) {
      int idx = tid + q * 256;
      const unsigned short* ga = (tk[q] < 0)
          ? Xzero
          : Xb + (size_t)tk[q] * DM + tt * 32 + asg[q] * 8;
      gload_lds16(ga, (char*)&Asl[buf][0][0] + (size_t)idx * 16);
    }
  };
  auto compute = [&](int buf) {
    short8 a[4], b[2];
#pragma unroll
    for (int m = 0; m < 4; ++m) {
      int R = wr * 64 + m * 16 + l15;
      a[m] = *(const short8*)((const char*)&Asl[buf][0][0] + R * 64 + ((l4 ^ sw) << 4));
    }
#pragma unroll
    for (int n = 0; n < 2; ++n)
      b[n] = *(const short8*)&Bsl[buf][l4][wc * 32 + n * 16 + l15][0];
#pragma unroll
    for (int m = 0; m < 4; ++m)
#pragma unroll
      for (int n = 0; n < 2; ++n)
        acc[m][n] = __builtin_amdgcn_mfma_f32_16x16x32_bf16(a[m], b[n], acc[m][n], 0, 0, 0);
  };

  issueB(0, bvA);
  issueA(0, 0);
  for (int kt = 0; kt < 32; kt += 2) {
    packwrite(bvA, 0);
    __syncthreads();
    if (kt + 1 < 32) { issueB(kt + 1, bvB); issueA(kt + 1, 1); }
    compute(0);
    packwrite(bvB, 1);
    __syncthreads();
    if (kt + 2 < 32) { issueB(kt + 2, bvA); issueA(kt + 2, 0); }
    compute(1);
  }

  float bias[2];
#pragma unroll
  for (int n = 0; n < 2; ++n) bias[n] = b1[e * HD + h0 + wc * 32 + n * 16 + l15];
#pragma unroll
  for (int m = 0; m < 4; ++m) {
#pragma unroll
    for (int n = 0; n < 2; ++n) {
      int col = h0 + wc * 32 + n * 16 + l15;
#pragma unroll
      for (int j = 0; j < 4; ++j) {
        int row = row0 + wr * 64 + m * 16 + l4 * 4 + j;
        float x = acc[m][n][j] + bias[n];
        float g = 0.5f * x * (1.f + tanhf(0.7978845608f * (x + 0.044715f * x * x * x)));
        Hbuf[(size_t)row * HD + col] = f2b(g);
      }
    }
  }
}

// ---------------------------------------------------------------- ffn2
// R10 structure, K-split x4: 64 units = (16 d-cols x 4 ks), 8 units/XCD,
// NT=16 K-steps/block, bf16 partials to Ypart; bias by ks==0 only.
__global__ __launch_bounds__(256, 6) void ffn2_mfma(
    const unsigned short* __restrict__ Hbuf,
    const float* __restrict__ W2,
    const float* __restrict__ b2,
    const int* __restrict__ tile_expert, const int* __restrict__ tile_row0,
    const int* __restrict__ n_tiles,
    unsigned short* __restrict__ Ypart) {
  int lin  = blockIdx.x;
  int xcd  = lin & 7, slot = lin >> 3;
  int unit = xcd * 8 + slot / TMAX;        // 0..63
  int t    = slot % TMAX;
  if (t >= n_tiles[0]) return;
  int e    = tile_expert[t];
  int row0 = tile_row0[t];
  int d0   = (unit >> 2) * 64;
  int ks   = unit & 3;
  int kbase = ks * (HD / KSPL);            // 0,512,1024,1536
  __shared__ __align__(16) unsigned short Asl[2][128][32];
  __shared__ __align__(16) unsigned short Bsl[2][4][64][8];
  int tid = threadIdx.x, lane = tid & 63;
  int wid = tid >> 6, wr = wid >> 1, wc = wid & 1;
  int l15 = lane & 15, l4 = lane >> 4;
  int sw  = (l15 >> 1) & 3;

  int ar[2], asg[2];
#pragma unroll
  for (int q = 0; q < 2; ++q) {
    int idx = tid + q * 256;
    ar[q]  = idx >> 2;
    asg[q] = (idx & 3) ^ ((ar[q] >> 1) & 3);
  }
  int bcol = tid & 63, bks = tid >> 6;
  const float* W2e = W2 + (size_t)e * HD * DM + (size_t)kbase * DM;

  f32x4 acc[4][2] = {};
  float bvA[8], bvB[8];

  auto issueB = [&](int tt, float* bv) {
    const float* p = W2e + (size_t)(tt * 32 + bks * 8) * DM + d0 + bcol;
#pragma unroll
    for (int i = 0; i < 8; ++i) bv[i] = p[(size_t)i * DM];
  };
  auto packwrite = [&](const float* bv, int buf) {
    u16x8 o;
#pragma unroll
    for (int i = 0; i < 8; ++i) o[i] = f2b(bv[i]);
    *(u16x8*)&Bsl[buf][bks][bcol][0] = o;
  };
  auto issueA = [&](int tt, int buf) {
#pragma unroll
    for (int q = 0; q < 2; ++q) {
      int idx = tid + q * 256;
      const unsigned short* ga =
          Hbuf + (size_t)(row0 + ar[q]) * HD + kbase + tt * 32 + asg[q] * 8;
      gload_lds16(ga, (char*)&Asl[buf][0][0] + (size_t)idx * 16);
    }
  };
  auto compute = [&](int buf) {
    short8 a[4], b[2];
#pragma unroll
    for (int m = 0; m < 4; ++m) {
      int R = wr * 64 + m * 16 + l15;
      a[m] = *(const short8*)((const char*)&Asl[buf][0][0] + R * 64 + ((l4 ^ sw) << 4));
    }
#pragma unroll
    for (int n = 0; n < 2; ++n)
      b[n] = *(const short8*)&Bsl[buf][l4][wc * 32 + n * 16 + l15][0];
#pragma unroll
    for (int m = 0; m < 4; ++m)
#pragma unroll
      for (int n = 0; n < 2; ++n)
        acc[m][n] = __builtin_amdgcn_mfma_f32_16x16x32_bf16(a[m], b[n], acc[m][n], 0, 0, 0);
  };

  const int NT = HD / KSPL / 32;           // 16 K-steps
  issueB(0, bvA);
  issueA(0, 0);
  for (int kt = 0; kt < NT; kt += 2) {
    packwrite(bvA, 0);
    __syncthreads();
    if (kt + 1 < NT) { issueB(kt + 1, bvB); issueA(kt + 1, 1); }
    compute(0);
    packwrite(bvB, 1);
    __syncthreads();
    if (kt + 2 < NT) { issueB(kt + 2, bvA); issueA(kt + 2, 0); }
    compute(1);
  }

  float bias[2];
#pragma unroll
  for (int n = 0; n < 2; ++n)
    bias[n] = (ks == 0) ? b2[e * DM + d0 + wc * 32 + n * 16 + l15] : 0.f;
  unsigned short* Yp = Ypart + (size_t)ks * RMAX * DM;
#pragma unroll
  for (int m = 0; m < 4; ++m) {
#pragma unroll
    for (int n = 0; n < 2; ++n) {
      int col = d0 + wc * 32 + n * 16 + l15;
#pragma unroll
      for (int j = 0; j < 4; ++j) {
        int row = row0 + wr * 64 + m * 16 + l4 * 4 + j;
        Yp[(size_t)row * DM + col] = f2b(acc[m][n][j] + bias[n]);
      }
    }
  }
}

// ---------------------------------------------------------------- combine
// out[n] = g0 * sum_ks Yp[ks][r0] + g1 * sum_ks Yp[ks][r1]
__global__ void combine_kernel(const unsigned short* __restrict__ Ypart,
                               const int* __restrict__ inv_g,
                               const float* __restrict__ gate_w,
                               float* __restrict__ out) {
  int n = blockIdx.x;
  int r0 = inv_g[n * 2], r1 = inv_g[n * 2 + 1];
  float g0 = gate_w[n * 2], g1 = gate_w[n * 2 + 1];
  int i = threadIdx.x;          // 256 threads x 4 elems
  float s0[4] = {0.f, 0.f, 0.f, 0.f};
  float s1[4] = {0.f, 0.f, 0.f, 0.f};
#pragma unroll
  for (int p = 0; p < KSPL; ++p) {
    const unsigned short* Yp = Ypart + (size_t)p * RMAX * DM;
    ushort4 a = *(const ushort4*)(Yp + (size_t)r0 * DM + i * 4);
    ushort4 b = *(const ushort4*)(Yp + (size_t)r1 * DM + i * 4);
    s0[0] += b2f(a.x); s0[1] += b2f(a.y); s0[2] += b2f(a.z); s0[3] += b2f(a.w);
    s1[0] += b2f(b.x); s1[1] += b2f(b.y); s1[2] += b2f(b.z); s1[3] += b2f(b.w);
  }
  float4 rv;
  rv.x = g0 * s0[0] + g1 * s1[0];
  rv.y = g0 * s0[1] + g1 * s1[1];
  rv.z = g0 * s0[2] + g1 * s1[2];
  rv.w = g0 * s0[3] + g1 * s1[3];
  *(float4*)(out + (size_t)n * DM + i * 4) = rv;
}

// ---------------------------------------------------------------- launch
extern "C" void kernel_launch(void* const* d_in, const int* in_sizes, int n_in,
                              void* d_out, int out_size, void* d_ws, size_t ws_size,
                              hipStream_t stream) {
  const float* inp = (const float*)d_in[0];
  const float* Wg  = (const float*)d_in[1];
  const float* bg  = (const float*)d_in[2];
  const float* W1  = (const float*)d_in[3];
  const float* b1  = (const float*)d_in[4];
  const float* W2  = (const float*)d_in[5];
  const float* b2  = (const float*)d_in[6];
  float* out = (float*)d_out;

  char* ws = (char*)d_ws;
  size_t off = 0;
  auto alloc = [&](size_t bytes) {
    size_t o = off;
    off = (off + bytes + 255) & ~(size_t)255;
    return o;
  };
  int*   top_idx     = (int*)  (ws + alloc(N_TOK * 2 * sizeof(int)));
  float* gate_w      = (float*)(ws + alloc(N_TOK * 2 * sizeof(float)));
  int*   token_of    = (int*)  (ws + alloc(RMAX * sizeof(int)));
  int*   inv_g       = (int*)  (ws + alloc(N_TOK * 2 * sizeof(int)));
  int*   tile_expert = (int*)  (ws + alloc(TMAX * sizeof(int)));
  int*   tile_row0   = (int*)  (ws + alloc(TMAX * sizeof(int)));
  int*   n_tiles     = (int*)  (ws + alloc(sizeof(int)));
  unsigned short* Xzero = (unsigned short*)(ws + alloc(DM * 2));
  unsigned short* Xb    = (unsigned short*)(ws + alloc((size_t)N_TOK * DM * 2));
  unsigned short* Hbuf  = (unsigned short*)(ws + alloc((size_t)RMAX * HD * 2));
  unsigned short* Ypart = (unsigned short*)(ws + alloc((size_t)KSPL * RMAX * DM * 2));
  (void)ws_size;

  hipMemsetAsync(Xzero, 0, DM * 2, stream);
  prep_kernel<<<PREP_BLKS, 256, 0, stream>>>(inp, Wg, bg, top_idx, gate_w, Xb);
  group_kernel<<<1, 1024, 0, stream>>>(top_idx, token_of, inv_g,
                                       tile_expert, tile_row0, n_tiles);
  ffn1_mfma<<<8 * 4 * TMAX, 256, 0, stream>>>(
      Xb, W1, b1, Xzero, token_of, tile_expert, tile_row0, n_tiles, Hbuf);
  ffn2_mfma<<<8 * 8 * TMAX, 256, 0, stream>>>(
      Hbuf, W2, b2, tile_expert, tile_row0, n_tiles, Ypart);
  combine_kernel<<<N_TOK, 256, 0, stream>>>(Ypart, inv_g, gate_w, out);
}

// Round 18
// 137.444 us; speedup vs baseline: 1.2220x; 1.1028x over previous
//
#include <hip/hip_runtime.h>
#include <math.h>

#define N_TOK 2048
#define DM    1024
#define HD    2048
#define NE    8
#define RMAX  5120                /* 4096 + 8*128 pad */
#define TMAX  40                  /* max 128-row tiles */
#define KSPL  2                   /* ffn2 K-split */

#define GATE_BLKS 512             /* N_TOK/4 */
#define XCVT_BLKS 1024            /* N_TOK*DM/(256*8) */
#define PREP_BLKS (GATE_BLKS + XCVT_BLKS)
#define WCV2_BLKS 512             /* W2: 8 experts x 64 k-tiles, 1024 thr */

typedef short short8 __attribute__((ext_vector_type(8)));
typedef unsigned short u16x8 __attribute__((ext_vector_type(8)));
typedef float f32x4  __attribute__((ext_vector_type(4)));

__device__ inline unsigned short f2b(float f) {   // fp32 -> bf16 RNE
  unsigned int u = __float_as_uint(f);
  return (unsigned short)((u + 0x7FFFu + ((u >> 16) & 1u)) >> 16);
}
__device__ inline float b2f(unsigned short s) {
  return __uint_as_float(((unsigned int)s) << 16);
}
__device__ inline void gload_lds16(const void* g, void* l) {
  __builtin_amdgcn_global_load_lds(
      (const __attribute__((address_space(1))) unsigned int*)g,
      (__attribute__((address_space(3))) unsigned int*)l, 16, 0, 0);
}

// ---------------------------------------------------------------- prep
// gate (512 blocks) + x-convert (1024 blocks). R10 exact.
__global__ __launch_bounds__(256) void prep_kernel(
    const float* __restrict__ inp, const float* __restrict__ Wg,
    const float* __restrict__ bg,
    int* __restrict__ top_idx, float* __restrict__ gate_w,
    unsigned short* __restrict__ Xb) {
  int bid = blockIdx.x;
  if (bid < GATE_BLKS) {
    int wave = threadIdx.x >> 6;
    int lane = threadIdx.x & 63;
    int n = bid * 4 + wave;
    float acc[NE];
#pragma unroll
    for (int e = 0; e < NE; ++e) acc[e] = 0.f;
    const float4* wg4 = reinterpret_cast<const float4*>(Wg);
#pragma unroll
    for (int i = 0; i < DM / 64; ++i) {
      int d = i * 64 + lane;
      float x = inp[n * DM + d];
      float4 w0 = wg4[d * 2 + 0];
      float4 w1 = wg4[d * 2 + 1];
      acc[0] += x * w0.x; acc[1] += x * w0.y; acc[2] += x * w0.z; acc[3] += x * w0.w;
      acc[4] += x * w1.x; acc[5] += x * w1.y; acc[6] += x * w1.z; acc[7] += x * w1.w;
    }
#pragma unroll
    for (int off = 32; off > 0; off >>= 1) {
#pragma unroll
      for (int e = 0; e < NE; ++e) acc[e] += __shfl_xor(acc[e], off);
    }
    if (lane == 0) {
      float v0 = -1e30f, v1 = -1e30f; int i0 = -1, i1 = -1;
#pragma unroll
      for (int e = 0; e < NE; ++e) {
        float v = acc[e] + bg[e];
        if (v > v0)      { v1 = v0; i1 = i0; v0 = v; i0 = e; }
        else if (v > v1) { v1 = v;  i1 = e; }
      }
      float e1 = expf(v1 - v0);
      float s  = 1.f + e1;
      top_idx[n * 2]     = i0;
      top_idx[n * 2 + 1] = i1;
      gate_w[n * 2]      = 1.f / s;
      gate_w[n * 2 + 1]  = e1 / s;
    }
  } else {
    int i = ((bid - GATE_BLKS) * 256 + threadIdx.x) * 8;
    float4 a = *(const float4*)(inp + i);
    float4 b = *(const float4*)(inp + i + 4);
    ushort4 pa, pb;
    pa.x = f2b(a.x); pa.y = f2b(a.y); pa.z = f2b(a.z); pa.w = f2b(a.w);
    pb.x = f2b(b.x); pb.y = f2b(b.y); pb.z = f2b(b.z); pb.w = f2b(b.w);
    *(ushort4*)(Xb + i)     = pa;
    *(ushort4*)(Xb + i + 4) = pb;
  }
}

// ---------------------------------------------------------------- group (+wcvt2 riders)
// Block 0: single-block deterministic bucketing (1024-thread scan).
// Blocks 1..512: convert W2 -> k-chunked bf16 on the otherwise-idle CUs.
// chunk (kb,n) = 8 consecutive k for col n, stored at ((kb*DM)+n)*8.
__global__ __launch_bounds__(1024) void group_kernel(
    const int* __restrict__ top_idx,
    const float* __restrict__ W2,
    int* __restrict__ token_of, int* __restrict__ inv_g,
    int* __restrict__ tile_expert, int* __restrict__ tile_row0,
    int* __restrict__ n_tiles,
    unsigned short* __restrict__ W2C) {
  if (blockIdx.x != 0) {
    // ---- rider: one 32k x 1024col tile of W2 per block
    int wb = blockIdx.x - 1;                 // 0..511
    int z  = wb >> 6;                        // expert
    int k0 = (wb & 63) * 32;
    const float* src = W2 + (size_t)z * HD * DM;
    unsigned short* dst = W2C + (size_t)z * HD * DM;
    int t  = threadIdx.x;
    int cg = t & 255, kg = t >> 8;           // 256 col-groups x 4 k-groups
    const float* s = src + (size_t)(k0 + kg * 8) * DM + cg * 4;
    float4 v[8];
#pragma unroll
    for (int i = 0; i < 8; ++i) v[i] = *(const float4*)(s + (size_t)i * DM);
#pragma unroll
    for (int c = 0; c < 4; ++c) {
      u16x8 o;
      o[0] = f2b(v[0][c]); o[1] = f2b(v[1][c]); o[2] = f2b(v[2][c]); o[3] = f2b(v[3][c]);
      o[4] = f2b(v[4][c]); o[5] = f2b(v[5][c]); o[6] = f2b(v[6][c]); o[7] = f2b(v[7][c]);
      *(u16x8*)(dst + ((size_t)(k0 / 8 + kg) * DM + cg * 4 + c) * 8) = o;
    }
    return;
  }
  __shared__ int s_wtot[16];
  int tid = threadIdx.x, lane = tid & 63, wid = tid >> 6;
  int base = 0, tiles = 0;
  for (int e = 0; e < NE; ++e) {
    int cnt = 0;
#pragma unroll
    for (int c0 = 0; c0 < N_TOK; c0 += 1024) {
      int n = c0 + tid;
      int t0 = top_idx[n * 2], t1 = top_idx[n * 2 + 1];
      bool f = (t0 == e) || (t1 == e);
      int k = (t0 == e) ? 0 : 1;
      unsigned long long m = __ballot(f);
      int lp = __popcll(m & ((1ull << lane) - 1ull));
      if (lane == 0) s_wtot[wid] = __popcll(m);
      __syncthreads();
      int wbase = 0, tot = 0;
#pragma unroll
      for (int w = 0; w < 16; ++w) {
        int c = s_wtot[w];
        if (w < wid) wbase += c;
        tot += c;
      }
      if (f) {
        int pos = base + cnt + wbase + lp;
        token_of[pos] = n;
        inv_g[n * 2 + k] = pos;
      }
      cnt += tot;
      __syncthreads();
    }
    int padded = (cnt + 127) & ~127;
    for (int i = cnt + tid; i < padded; i += 1024) token_of[base + i] = -1;
    if (tid == 0) {
      for (int t = 0; t < padded / 128; ++t) {
        tile_expert[tiles + t] = e;
        tile_row0[tiles + t]   = base + t * 128;
      }
    }
    tiles += padded / 128;
    base  += padded;
    __syncthreads();
  }
  if (tid == 0) n_tiles[0] = tiles;
}

// ---------------------------------------------------------------- ffn1
// R10 exact: 128x64 tile, BK=32, dbuf, XCD swizzle (4 units/XCD).
// A: bf16 gload_lds slot-swizzled; B: fp32 W1 -> reg -> bf16 -> ds_write.
__global__ __launch_bounds__(256, 6) void ffn1_mfma(
    const unsigned short* __restrict__ Xb,
    const float* __restrict__ W1,
    const float* __restrict__ b1,
    const unsigned short* __restrict__ Xzero,
    const int* __restrict__ token_of, const int* __restrict__ tile_expert,
    const int* __restrict__ tile_row0, const int* __restrict__ n_tiles,
    unsigned short* __restrict__ Hbuf) {
  int lin  = blockIdx.x;
  int xcd  = lin & 7, slot = lin >> 3;
  int unit = xcd * 4 + slot / TMAX;        // 0..31 col unit
  int t    = slot % TMAX;
  if (t >= n_tiles[0]) return;
  int e    = tile_expert[t];
  int row0 = tile_row0[t];
  int h0   = unit * 64;
  __shared__ __align__(16) unsigned short Asl[2][128][32];
  __shared__ __align__(16) unsigned short Bsl[2][4][64][8];
  int tid = threadIdx.x, lane = tid & 63;
  int wid = tid >> 6, wr = wid >> 1, wc = wid & 1;
  int l15 = lane & 15, l4 = lane >> 4;
  int sw  = (l15 >> 1) & 3;

  int ar[2], asg[2], tk[2];
#pragma unroll
  for (int q = 0; q < 2; ++q) {
    int idx = tid + q * 256;
    ar[q]  = idx >> 2;
    asg[q] = (idx & 3) ^ ((ar[q] >> 1) & 3);
    tk[q]  = token_of[row0 + ar[q]];
  }
  int bcol = tid & 63, bks = tid >> 6;
  const float* W1e = W1 + (size_t)e * DM * HD;

  f32x4 acc[4][2] = {};
  float bvA[8], bvB[8];

  auto issueB = [&](int tt, float* bv) {
    const float* p = W1e + (size_t)(tt * 32 + bks * 8) * HD + h0 + bcol;
#pragma unroll
    for (int i = 0; i < 8; ++i) bv[i] = p[(size_t)i * HD];
  };
  auto packwrite = [&](const float* bv, int buf) {
    u16x8 o;
#pragma unroll
    for (int i = 0; i < 8; ++i) o[i] = f2b(bv[i]);
    *(u16x8*)&Bsl[buf][bks][bcol][0] = o;
  };
  auto issueA = [&](int tt, int buf) {
#pragma unroll
    for (int q = 0; q < 2; ++q) {
      int idx = tid + q * 256;
      const unsigned short* ga = (tk[q] < 0)
          ? Xzero
          : Xb + (size_t)tk[q] * DM + tt * 32 + asg[q] * 8;
      gload_lds16(ga, (char*)&Asl[buf][0][0] + (size_t)idx * 16);
    }
  };
  auto compute = [&](int buf) {
    short8 a[4], b[2];
#pragma unroll
    for (int m = 0; m < 4; ++m) {
      int R = wr * 64 + m * 16 + l15;
      a[m] = *(const short8*)((const char*)&Asl[buf][0][0] + R * 64 + ((l4 ^ sw) << 4));
    }
#pragma unroll
    for (int n = 0; n < 2; ++n)
      b[n] = *(const short8*)&Bsl[buf][l4][wc * 32 + n * 16 + l15][0];
#pragma unroll
    for (int m = 0; m < 4; ++m)
#pragma unroll
      for (int n = 0; n < 2; ++n)
        acc[m][n] = __builtin_amdgcn_mfma_f32_16x16x32_bf16(a[m], b[n], acc[m][n], 0, 0, 0);
  };

  issueB(0, bvA);
  issueA(0, 0);
  for (int kt = 0; kt < 32; kt += 2) {
    packwrite(bvA, 0);
    __syncthreads();
    if (kt + 1 < 32) { issueB(kt + 1, bvB); issueA(kt + 1, 1); }
    compute(0);
    packwrite(bvB, 1);
    __syncthreads();
    if (kt + 2 < 32) { issueB(kt + 2, bvA); issueA(kt + 2, 0); }
    compute(1);
  }

  float bias[2];
#pragma unroll
  for (int n = 0; n < 2; ++n) bias[n] = b1[e * HD + h0 + wc * 32 + n * 16 + l15];
#pragma unroll
  for (int m = 0; m < 4; ++m) {
#pragma unroll
    for (int n = 0; n < 2; ++n) {
      int col = h0 + wc * 32 + n * 16 + l15;
#pragma unroll
      for (int j = 0; j < 4; ++j) {
        int row = row0 + wr * 64 + m * 16 + l4 * 4 + j;
        float x = acc[m][n][j] + bias[n];
        float g = 0.5f * x * (1.f + tanhf(0.7978845608f * (x + 0.044715f * x * x * x)));
        Hbuf[(size_t)row * HD + col] = f2b(g);
      }
    }
  }
}

// ---------------------------------------------------------------- ffn2
// R13 exact: both operands bf16 via pure global_load_lds (A: Hbuf slot-
// swizzled; B: W2C k-chunked); K-split x2; fp32 partials; bias ks==0 only.
__global__ __launch_bounds__(256, 6) void ffn2_mfma(
    const unsigned short* __restrict__ Hbuf,
    const unsigned short* __restrict__ W2C,
    const float* __restrict__ b2,
    const int* __restrict__ tile_expert, const int* __restrict__ tile_row0,
    const int* __restrict__ n_tiles,
    float* __restrict__ Ypart) {
  int lin  = blockIdx.x;
  int xcd  = lin & 7, slot = lin >> 3;
  int unit = xcd * 4 + slot / TMAX;        // 0..31
  int t    = slot % TMAX;
  if (t >= n_tiles[0]) return;
  int e    = tile_expert[t];
  int row0 = tile_row0[t];
  int d0   = (unit >> 1) * 64;
  int ks   = unit & 1;
  int kbase = ks * (HD / KSPL);            // 0 or 1024
  int kb0   = kbase >> 3;                  // chunk-row base
  __shared__ __align__(16) unsigned short Asl[2][128][32];
  __shared__ __align__(16) unsigned short Bsl[2][4][64][8];
  int tid = threadIdx.x, lane = tid & 63;
  int wid = tid >> 6, wr = wid >> 1, wc = wid & 1;
  int l15 = lane & 15, l4 = lane >> 4;
  int sw  = (l15 >> 1) & 3;

  int ar[2], asg[2];
#pragma unroll
  for (int q = 0; q < 2; ++q) {
    int idx = tid + q * 256;
    ar[q]  = idx >> 2;
    asg[q] = (idx & 3) ^ ((ar[q] >> 1) & 3);
  }
  int bcol = tid & 63, bks = tid >> 6;
  const unsigned short* W2e = W2C + (size_t)e * HD * DM;

  f32x4 acc[4][2] = {};

  auto issueAB = [&](int tt, int buf) {
#pragma unroll
    for (int q = 0; q < 2; ++q) {
      int idx = tid + q * 256;
      const unsigned short* ga =
          Hbuf + (size_t)(row0 + ar[q]) * HD + kbase + tt * 32 + asg[q] * 8;
      gload_lds16(ga, (char*)&Asl[buf][0][0] + (size_t)idx * 16);
    }
    const unsigned short* gb =
        W2e + ((size_t)(kb0 + tt * 4 + bks) * DM + d0 + bcol) * 8;
    gload_lds16(gb, (char*)&Bsl[buf][0][0] + (size_t)tid * 16);
  };
  auto compute = [&](int buf) {
    short8 a[4], b[2];
#pragma unroll
    for (int m = 0; m < 4; ++m) {
      int R = wr * 64 + m * 16 + l15;
      a[m] = *(const short8*)((const char*)&Asl[buf][0][0] + R * 64 + ((l4 ^ sw) << 4));
    }
#pragma unroll
    for (int n = 0; n < 2; ++n)
      b[n] = *(const short8*)&Bsl[buf][l4][wc * 32 + n * 16 + l15][0];
#pragma unroll
    for (int m = 0; m < 4; ++m)
#pragma unroll
      for (int n = 0; n < 2; ++n)
        acc[m][n] = __builtin_amdgcn_mfma_f32_16x16x32_bf16(a[m], b[n], acc[m][n], 0, 0, 0);
  };

  const int NT = HD / KSPL / 32;           // 32 K-steps
  issueAB(0, 0);
  for (int kt = 0; kt < NT; kt += 2) {
    __syncthreads();                       // drains vmcnt: buf0 ready
    if (kt + 1 < NT) issueAB(kt + 1, 1);
    compute(0);
    __syncthreads();                       // buf1 ready; buf0 free
    if (kt + 2 < NT) issueAB(kt + 2, 0);
    compute(1);
  }

  float bias[2];
#pragma unroll
  for (int n = 0; n < 2; ++n)
    bias[n] = (ks == 0) ? b2[e * DM + d0 + wc * 32 + n * 16 + l15] : 0.f;
  float* Yp = Ypart + (size_t)ks * RMAX * DM;
#pragma unroll
  for (int m = 0; m < 4; ++m) {
#pragma unroll
    for (int n = 0; n < 2; ++n) {
      int col = d0 + wc * 32 + n * 16 + l15;
#pragma unroll
      for (int j = 0; j < 4; ++j) {
        int row = row0 + wr * 64 + m * 16 + l4 * 4 + j;
        Yp[(size_t)row * DM + col] = acc[m][n][j] + bias[n];
      }
    }
  }
}

// ---------------------------------------------------------------- combine
__global__ void combine_kernel(const float* __restrict__ Ypart,
                               const int* __restrict__ inv_g,
                               const float* __restrict__ gate_w,
                               float* __restrict__ out) {
  int n = blockIdx.x;
  int r0 = inv_g[n * 2], r1 = inv_g[n * 2 + 1];
  float g0 = gate_w[n * 2], g1 = gate_w[n * 2 + 1];
  int i = threadIdx.x;
  const float4* y00 = (const float4*)(Ypart + (size_t)r0 * DM);
  const float4* y01 = (const float4*)(Ypart + (size_t)(RMAX + r0) * DM);
  const float4* y10 = (const float4*)(Ypart + (size_t)r1 * DM);
  const float4* y11 = (const float4*)(Ypart + (size_t)(RMAX + r1) * DM);
  float4 a0 = y00[i], a1 = y01[i], b0 = y10[i], b1 = y11[i];
  float4 rv;
  rv.x = g0 * (a0.x + a1.x) + g1 * (b0.x + b1.x);
  rv.y = g0 * (a0.y + a1.y) + g1 * (b0.y + b1.y);
  rv.z = g0 * (a0.z + a1.z) + g1 * (b0.z + b1.z);
  rv.w = g0 * (a0.w + a1.w) + g1 * (b0.w + b1.w);
  *(float4*)(out + (size_t)n * DM + i * 4) = rv;
}

// ---------------------------------------------------------------- launch
extern "C" void kernel_launch(void* const* d_in, const int* in_sizes, int n_in,
                              void* d_out, int out_size, void* d_ws, size_t ws_size,
                              hipStream_t stream) {
  const float* inp = (const float*)d_in[0];
  const float* Wg  = (const float*)d_in[1];
  const float* bg  = (const float*)d_in[2];
  const float* W1  = (const float*)d_in[3];
  const float* b1  = (const float*)d_in[4];
  const float* W2  = (const float*)d_in[5];
  const float* b2  = (const float*)d_in[6];
  float* out = (float*)d_out;

  char* ws = (char*)d_ws;
  size_t off = 0;
  auto alloc = [&](size_t bytes) {
    size_t o = off;
    off = (off + bytes + 255) & ~(size_t)255;
    return o;
  };
  int*   top_idx     = (int*)  (ws + alloc(N_TOK * 2 * sizeof(int)));
  float* gate_w      = (float*)(ws + alloc(N_TOK * 2 * sizeof(float)));
  int*   token_of    = (int*)  (ws + alloc(RMAX * sizeof(int)));
  int*   inv_g       = (int*)  (ws + alloc(N_TOK * 2 * sizeof(int)));
  int*   tile_expert = (int*)  (ws + alloc(TMAX * sizeof(int)));
  int*   tile_row0   = (int*)  (ws + alloc(TMAX * sizeof(int)));
  int*   n_tiles     = (int*)  (ws + alloc(sizeof(int)));
  unsigned short* Xzero = (unsigned short*)(ws + alloc(DM * 2));
  unsigned short* Xb    = (unsigned short*)(ws + alloc((size_t)N_TOK * DM * 2));
  unsigned short* W2C   = (unsigned short*)(ws + alloc((size_t)NE * HD * DM * 2));
  unsigned short* Hbuf  = (unsigned short*)(ws + alloc((size_t)RMAX * HD * 2));
  float*          Ypart = (float*)(ws + alloc((size_t)KSPL * RMAX * DM * 4));
  (void)ws_size;

  hipMemsetAsync(Xzero, 0, DM * 2, stream);
  prep_kernel<<<PREP_BLKS, 256, 0, stream>>>(inp, Wg, bg, top_idx, gate_w, Xb);
  group_kernel<<<1 + WCV2_BLKS, 1024, 0, stream>>>(
      top_idx, W2, token_of, inv_g, tile_expert, tile_row0, n_tiles, W2C);
  ffn1_mfma<<<8 * 4 * TMAX, 256, 0, stream>>>(
      Xb, W1, b1, Xzero, token_of, tile_expert, tile_row0, n_tiles, Hbuf);
  ffn2_mfma<<<8 * 4 * TMAX, 256, 0, stream>>>(
      Hbuf, W2C, b2, tile_expert, tile_row0, n_tiles, Ypart);
  combine_kernel<<<N_TOK, 256, 0, stream>>>(Ypart, inv_g, gate_w, out);
}